// Round 4
// baseline (813.576 us; speedup 1.0000x reference)
//
#include <hip/hip_runtime.h>
#include <hip/hip_bf16.h>
#include <hip/hip_fp8.h>
#include <stdint.h>

#define NN 16384
#define DD 512
#define MARGINV 2.0f
#define EPSV 1e-6f
#define INFV 3.0e38f

#define BJ 32
#define JGROUPS 8
#define JRANGE (NN / JGROUPS)   // 2048
#define NTILES (JRANGE / BJ)    // 64
#define ROWQ 512                // fp8 row bytes
#define TILEB (BJ * ROWQ)       // 16384 B per tile buffer

typedef __attribute__((ext_vector_type(4))) float f32x4;
typedef __attribute__((ext_vector_type(4))) int   i32x4;
typedef __attribute__((ext_vector_type(8))) int   i32x8;

#define UNIT_SCALE 0x7F   // E8M0 biased exponent 127 -> x1.0

// lexicographic (val, idx) insert into a sorted-2 list
__device__ inline void ins2(float v, int ix, float& b0, int& x0, float& b1, int& x1) {
  bool l1 = (v < b1) || (v == b1 && ix < x1);
  if (l1) {
    bool l0 = (v < b0) || (v == b0 && ix < x0);
    b1 = l0 ? b0 : v;  x1 = l0 ? x0 : ix;
    b0 = l0 ? v : b0;  x0 = l0 ? ix : x0;
  }
}

// ---------------- Kernel 1: row squared norms (fp32) + fp8 e4m3 quantize ----------------
extern "C" __global__ __launch_bounds__(256)
void prep_kernel(const float* __restrict__ x, unsigned char* __restrict__ xq,
                 float* __restrict__ sq, float* __restrict__ out) {
  if (blockIdx.x == 0 && threadIdx.x == 0) out[0] = 0.0f;   // replaces memset dispatch
  int row  = blockIdx.x * 4 + (threadIdx.x >> 6);
  int lane = threadIdx.x & 63;
  const float* xr = x + (size_t)row * DD + lane * 8;
  f32x4 a = *(const f32x4*)xr;
  f32x4 b = *(const f32x4*)(xr + 4);
  float s = a[0]*a[0]+a[1]*a[1]+a[2]*a[2]+a[3]*a[3]
          + b[0]*b[0]+b[1]*b[1]+b[2]*b[2]+b[3]*b[3];
  #pragma unroll
  for (int off = 1; off < 64; off <<= 1) s += __shfl_xor(s, off, 64);
  unsigned long long pk = 0;
  #pragma unroll
  for (int t = 0; t < 4; ++t) {
    __hip_fp8_e4m3 qa(a[t]), qb(b[t]);
    pk |= ((unsigned long long)qa.__x) << (8 * t);
    pk |= ((unsigned long long)qb.__x) << (8 * (t + 4));
  }
  *(unsigned long long*)(xq + (size_t)row * ROWQ + lane * 8) = pk;
  if (lane == 0) sq[row] = s;
}

// ---------------- Kernel 2: fused MX-fp8 GEMM (X·X^T) + per-row top-2 (self excluded) ----
// mfma_scale_f32_16x16x128_f8f6f4, fp8 e4m3 A/B, unit scales -> bit-identical to
// non-scaled fp8 dot but at the MX rate (2x MFMA pipe throughput).
// block = 256 thr (4 waves) covers 128 i-rows x one j-group of 2048; BJ=32 j/tile.
// Per wave: 2 A-sets of 16 i-rows (64 regs); per 32-B B-fragment (2 ds_read_b128)
// -> 2 MFMAs. K-permutation (identical for A and B; dot invariant): lane's k-slice
// of chunk c = row bytes [c*128 + quad*32, +32).
// LDS 16B-chunk swizzle u_lds = u_glob ^ (row & 7) (applied on the global_load_lds
// source address; reader un-swizzles).
extern "C" __global__ __launch_bounds__(256, 4)
void knn_kernel(const unsigned char* __restrict__ xq, const float* __restrict__ sq,
                float* __restrict__ pv, int* __restrict__ pi) {
  __shared__ __align__(16) char lds[2 * TILEB];  // 32,768 B
  const int tid  = threadIdx.x;
  const int wave = tid >> 6;
  const int lane = tid & 63;
  const int quad = lane >> 4;
  const int r16  = lane & 15;
  const int bi   = blockIdx.x >> 3;             // 0..127
  const int bj   = blockIdx.x & 7;
  const int ibase = bi * 128 + wave * 32;       // 32 i-rows per wave
  const int jbase = bj * JRANGE;

  // A fragments: 2 sets x 4 k-chunks x 32 B (v8i32). A[m=r16][k=chunk*128+quad*32+t]
  i32x8 a0[4], a1[4];
  {
    const unsigned char* ar0 = xq + (size_t)(ibase + r16)      * ROWQ + quad * 32;
    const unsigned char* ar1 = xq + (size_t)(ibase + 16 + r16) * ROWQ + quad * 32;
    #pragma unroll
    for (int c = 0; c < 4; ++c) {
      i32x4 lo0 = *(const i32x4*)(ar0 + c * 128);
      i32x4 hi0 = *(const i32x4*)(ar0 + c * 128 + 16);
      i32x4 lo1 = *(const i32x4*)(ar1 + c * 128);
      i32x4 hi1 = *(const i32x4*)(ar1 + c * 128 + 16);
      a0[c] = i32x8{lo0[0],lo0[1],lo0[2],lo0[3],hi0[0],hi0[1],hi0[2],hi0[3]};
      a1[c] = i32x8{lo1[0],lo1[1],lo1[2],lo1[3],hi1[0],hi1[1],hi1[2],hi1[3]};
    }
  }

  // top-2 per (set s, reg r): q = s*4 + r; i-row = ibase + s*16 + quad*4 + r
  float t0v[8], t1v[8];
  int   t0i[8], t1i[8];
  #pragma unroll
  for (int q = 0; q < 8; ++q) { t0v[q] = t1v[q] = INFV; t0i[q] = t1i[q] = 0x7FFFFFFF; }

  auto stage = [&](int jt, int buf) {
    const int jrow0 = jbase + jt * BJ;
    #pragma unroll
    for (int p = 0; p < 4; ++p) {
      const int rr = wave * 8 + p * 2;                     // wave-uniform local row pair
      const int lr = rr + (lane >> 5);                     // per-lane local row
      const int u  = (lane & 31) ^ (lr & 7);               // swizzled global 16B-chunk
      const unsigned char* gsrc = xq + (size_t)(jrow0 + lr) * ROWQ + u * 16;
      char* ldst = lds + buf * TILEB + rr * ROWQ;          // wave-uniform base
      __builtin_amdgcn_global_load_lds((const __attribute__((address_space(1))) void*)gsrc,
                                       (__attribute__((address_space(3))) void*)ldst,
                                       16, 0, 0);
    }
  };

  const int sw = r16 & 7;
  stage(0, 0);
  for (int jt = 0; jt < NTILES; ++jt) {
    __syncthreads();
    if (jt + 1 < NTILES) stage(jt + 1, (jt + 1) & 1);
    #pragma unroll
    for (int jh = 0; jh < 2; ++jh) {
      const char* brow = lds + (jt & 1) * TILEB + (jh * 16 + r16) * ROWQ;
      f32x4 acc0 = {0.f, 0.f, 0.f, 0.f};
      f32x4 acc1 = {0.f, 0.f, 0.f, 0.f};
      #pragma unroll
      for (int c = 0; c < 4; ++c) {
        const int g0 = c * 8 + quad * 2;
        i32x4 lo = *(const i32x4*)(brow + ((g0       ^ sw) * 16));
        i32x4 hi = *(const i32x4*)(brow + (((g0 + 1) ^ sw) * 16));
        i32x8 bf = i32x8{lo[0],lo[1],lo[2],lo[3],hi[0],hi[1],hi[2],hi[3]};
        acc0 = __builtin_amdgcn_mfma_scale_f32_16x16x128_f8f6f4(
                 a0[c], bf, acc0, 0, 0, 0, UNIT_SCALE, 0, UNIT_SCALE);
        acc1 = __builtin_amdgcn_mfma_scale_f32_16x16x128_f8f6f4(
                 a1[c], bf, acc1, 0, 0, 0, UNIT_SCALE, 0, UNIT_SCALE);
      }
      const int j = jbase + jt * BJ + jh * 16 + r16;
      const float sqj = sq[j];
      #pragma unroll
      for (int r = 0; r < 4; ++r) {
        const int gi0 = ibase + quad * 4 + r;
        float v0 = fmaf(-2.0f, acc0[r], sqj);
        v0 = (j == gi0) ? INFV : v0;                       // exclude self
        if (v0 < t1v[r]) {                                 // j increasing: strict < keeps lowest idx on ties
          bool l0 = v0 < t0v[r];
          t1v[r] = l0 ? t0v[r] : v0;  t1i[r] = l0 ? t0i[r] : j;
          t0v[r] = l0 ? v0 : t0v[r];  t0i[r] = l0 ? j : t0i[r];
        }
        const int q = 4 + r;
        float v1 = fmaf(-2.0f, acc1[r], sqj);
        v1 = (j == gi0 + 16) ? INFV : v1;
        if (v1 < t1v[q]) {
          bool l0 = v1 < t0v[q];
          t1v[q] = l0 ? t0v[q] : v1;  t1i[q] = l0 ? t0i[q] : j;
          t0v[q] = l0 ? v1 : t0v[q];  t0i[q] = l0 ? j : t0i[q];
        }
      }
    }
  }

  // ------- in-register butterfly merge across r16 (masks 1,2,4,8 stay in-quad) -------
  #pragma unroll
  for (int m = 1; m <= 8; m <<= 1) {
    #pragma unroll
    for (int q = 0; q < 8; ++q) {
      float ov0 = __shfl_xor(t0v[q], m, 64); int oi0 = __shfl_xor(t0i[q], m, 64);
      float ov1 = __shfl_xor(t1v[q], m, 64); int oi1 = __shfl_xor(t1i[q], m, 64);
      ins2(ov0, oi0, t0v[q], t0i[q], t1v[q], t1i[q]);
      ins2(ov1, oi1, t0v[q], t0i[q], t1v[q], t1i[q]);
    }
  }

  // lane with r16 == q writes row q's merged top-2
  #pragma unroll
  for (int q = 0; q < 8; ++q) {
    if (r16 == q) {
      int s  = q >> 2, r = q & 3;
      int gi = ibase + s * 16 + quad * 4 + r;
      int ob = (gi * JGROUPS + bj) * 2;
      pv[ob + 0] = t0v[q]; pv[ob + 1] = t1v[q];
      pi[ob + 0] = t0i[q]; pi[ob + 1] = t1i[q];
    }
  }
}

// ---------------- Kernel 3: merge partials, fp32 norms, hinge, mean ----------------
extern "C" __global__ __launch_bounds__(256)
void finalize_kernel(const float* __restrict__ x, const float* __restrict__ pos,
                     const float* __restrict__ pv, const int* __restrict__ pi,
                     float* __restrict__ out) {
  __shared__ float wsum[4];
  int i    = blockIdx.x * 4 + (threadIdx.x >> 6);
  int wave = threadIdx.x >> 6;
  int lane = threadIdx.x & 63;
  int neg = 0;
  if (lane == 0) {
    float b0 = INFV, b1 = INFV;
    int   x0 = 0x7FFFFFFF, x1 = 0x7FFFFFFF;
    #pragma unroll
    for (int s = 0; s < JGROUPS * 2; ++s) {
      ins2(pv[i * (JGROUPS * 2) + s], pi[i * (JGROUPS * 2) + s], b0, x0, b1, x1);
    }
    neg = x1;   // 2nd NN excluding self == reference idx3[:,2]
  }
  neg = __shfl(neg, 0, 64);
  const float* xr = x   + (size_t)i * DD + lane * 8;
  const float* pr = pos + (size_t)i * DD + lane * 8;
  const float* nr = x   + (size_t)neg * DD + lane * 8;
  f32x4 xa = *(const f32x4*)xr, xb4 = *(const f32x4*)(xr + 4);
  f32x4 pa = *(const f32x4*)pr, pb  = *(const f32x4*)(pr + 4);
  f32x4 na = *(const f32x4*)nr, nb  = *(const f32x4*)(nr + 4);
  float sap = 0.f, san = 0.f;
  #pragma unroll
  for (int k = 0; k < 4; ++k) {
    float d0 = xa[k]  - pa[k] + EPSV; sap = fmaf(d0, d0, sap);
    float d1 = xa[k]  - na[k] + EPSV; san = fmaf(d1, d1, san);
    float d2 = xb4[k] - pb[k] + EPSV; sap = fmaf(d2, d2, sap);
    float d3 = xb4[k] - nb[k] + EPSV; san = fmaf(d3, d3, san);
  }
  #pragma unroll
  for (int off = 1; off < 64; off <<= 1) {
    sap += __shfl_xor(sap, off, 64);
    san += __shfl_xor(san, off, 64);
  }
  if (lane == 0) {
    float l = sqrtf(sap) - sqrtf(san) + MARGINV;
    wsum[wave] = l > 0.f ? l : 0.f;
  }
  __syncthreads();
  if (threadIdx.x == 0) {
    atomicAdd(out, (wsum[0] + wsum[1] + wsum[2] + wsum[3]) * (1.0f / NN));
  }
}

// ---------------- host ----------------
extern "C" void kernel_launch(void* const* d_in, const int* in_sizes, int n_in,
                              void* d_out, int out_size, void* d_ws, size_t ws_size,
                              hipStream_t stream) {
  const float* x   = (const float*)d_in[0];
  const float* pos = (const float*)d_in[1];
  char* ws = (char*)d_ws;
  unsigned char* xq = (unsigned char*)ws;                                 // 8 MB
  float* sq = (float*)(ws + (size_t)NN * ROWQ);                           // 64 KB
  float* pv = (float*)(ws + (size_t)NN * ROWQ + (size_t)NN * 4);          // 1 MB
  int*   pi = (int*)  (ws + (size_t)NN * ROWQ + (size_t)NN * 4
                          + (size_t)NN * JGROUPS * 2 * 4);                // 1 MB

  prep_kernel<<<NN / 4, 256, 0, stream>>>(x, xq, sq, (float*)d_out);
  knn_kernel<<<(NN / 128) * JGROUPS, 256, 0, stream>>>(xq, sq, pv, pi);
  finalize_kernel<<<NN / 4, 256, 0, stream>>>(x, pos, pv, pi, (float*)d_out);
}

// Round 5
// 291.586 us; speedup vs baseline: 2.7902x; 2.7902x over previous
//
#include <hip/hip_runtime.h>
#include <hip/hip_bf16.h>
#include <hip/hip_fp8.h>
#include <stdint.h>

#define NN 16384
#define DD 512
#define MARGINV 2.0f
#define EPSV 1e-6f

#define BJ 32
#define JGROUPS 8
#define JRANGE (NN / JGROUPS)   // 2048
#define NTILES (JRANGE / BJ)    // 64
#define ROWQ 512                // fp8 row bytes
#define TILEB (BJ * ROWQ)       // 16384 B per tile buffer

#define KEYMASK 0xFFFFC000      // keep sign+exp+9 mantissa bits; low 14 = j
#define KEYINIT 0x7FFFFFFF

typedef __attribute__((ext_vector_type(4))) float f32x4;
typedef __attribute__((ext_vector_type(4))) int   i32x4;
typedef __attribute__((ext_vector_type(8))) int   i32x8;

#define UNIT_SCALE 0x7F   // E8M0 biased exponent 127 -> x1.0

__device__ inline int imin(int a, int b) { return a < b ? a : b; }
__device__ inline int imax(int a, int b) { return a > b ? a : b; }

// streaming insert of one packed key into a sorted-3 list (5 min/max ops)
__device__ inline void kins(int u, int& m0, int& m1, int& m2) {
  int t  = imax(m0, u); m0 = imin(m0, u);
  int t2 = imax(m1, t); m1 = imin(m1, t);
  m2 = imin(m2, t2);
}

// ---------------- Kernel 1: row squared norms (fp32) + fp8 e4m3 quantize ----------------
extern "C" __global__ __launch_bounds__(256)
void prep_kernel(const float* __restrict__ x, unsigned char* __restrict__ xq,
                 float* __restrict__ sq, float* __restrict__ out) {
  if (blockIdx.x == 0 && threadIdx.x == 0) out[0] = 0.0f;   // replaces memset dispatch
  int row  = blockIdx.x * 4 + (threadIdx.x >> 6);
  int lane = threadIdx.x & 63;
  const float* xr = x + (size_t)row * DD + lane * 8;
  f32x4 a = *(const f32x4*)xr;
  f32x4 b = *(const f32x4*)(xr + 4);
  float s = a[0]*a[0]+a[1]*a[1]+a[2]*a[2]+a[3]*a[3]
          + b[0]*b[0]+b[1]*b[1]+b[2]*b[2]+b[3]*b[3];
  #pragma unroll
  for (int off = 1; off < 64; off <<= 1) s += __shfl_xor(s, off, 64);
  unsigned long long pk = 0;
  #pragma unroll
  for (int t = 0; t < 4; ++t) {
    __hip_fp8_e4m3 qa(a[t]), qb(b[t]);
    pk |= ((unsigned long long)qa.__x) << (8 * t);
    pk |= ((unsigned long long)qb.__x) << (8 * (t + 4));
  }
  *(unsigned long long*)(xq + (size_t)row * ROWQ + lane * 8) = pk;
  if (lane == 0) sq[row] = s;
}

// ---------------- Kernel 2: fused MX-fp8 GEMM (X·X^T) + per-row packed top-3 -------------
// mfma_scale_f32_16x16x128_f8f6f4 (fp8 e4m3, unit scales == plain fp8 dot, 2x rate).
// block = 256 thr (4 waves) covers 128 i-rows x one j-group of 2048; BJ=32 j/tile.
// Per wave: 2 A-sets of 16 i-rows (64 VGPR); each 32-B B-fragment -> 2 MFMAs.
// Top-3 as packed int keys: (float_bits(max(d2,0)) & 0xFFFFC000) | j.
//   - int-monotonic for d2>=0; ties pick lowest j (== lax.top_k order)
//   - self kept (d2~0, always rank 0 by >700 margin) -> rank 2 == idx3[:,2]
//   - 24 regs state, branchless 8-op update per element (spill-proof vs round 4)
// __launch_bounds__(256,3): VGPR cap 170 -- never spill; 4 waves/SIMD if fits 128.
extern "C" __global__ __launch_bounds__(256, 3)
void knn_kernel(const unsigned char* __restrict__ xq, const float* __restrict__ sq,
                int* __restrict__ pk) {
  __shared__ __align__(16) char lds[2 * TILEB];  // 32,768 B
  const int tid  = threadIdx.x;
  const int wave = tid >> 6;
  const int lane = tid & 63;
  const int quad = lane >> 4;
  const int r16  = lane & 15;
  const int bi   = blockIdx.x >> 3;             // 0..127
  const int bj   = blockIdx.x & 7;
  const int ibase = bi * 128 + wave * 32;       // 32 i-rows per wave
  const int jbase = bj * JRANGE;

  // A fragments: 2 sets x 4 k-chunks x 32 B (v8i32). A[m=r16][k=chunk*128+quad*32+t]
  i32x8 a0[4], a1[4];
  {
    const unsigned char* ar0 = xq + (size_t)(ibase + r16)      * ROWQ + quad * 32;
    const unsigned char* ar1 = xq + (size_t)(ibase + 16 + r16) * ROWQ + quad * 32;
    #pragma unroll
    for (int c = 0; c < 4; ++c) {
      i32x4 lo0 = *(const i32x4*)(ar0 + c * 128);
      i32x4 hi0 = *(const i32x4*)(ar0 + c * 128 + 16);
      i32x4 lo1 = *(const i32x4*)(ar1 + c * 128);
      i32x4 hi1 = *(const i32x4*)(ar1 + c * 128 + 16);
      a0[c] = i32x8{lo0[0],lo0[1],lo0[2],lo0[3],hi0[0],hi0[1],hi0[2],hi0[3]};
      a1[c] = i32x8{lo1[0],lo1[1],lo1[2],lo1[3],hi1[0],hi1[1],hi1[2],hi1[3]};
    }
  }

  // packed top-3 per (set s, reg r): q = s*4 + r; i-row = ibase + s*16 + quad*4 + r
  int m0[8], m1[8], m2[8];
  #pragma unroll
  for (int q = 0; q < 8; ++q) { m0[q] = m1[q] = m2[q] = KEYINIT; }

  // jt-invariant swizzled B chunk offsets
  const int sw = r16 & 7;
  int boff[8];
  #pragma unroll
  for (int c = 0; c < 4; ++c) {
    const int g0 = c * 8 + quad * 2;
    boff[2*c]   = (g0       ^ sw) * 16;
    boff[2*c+1] = ((g0 + 1) ^ sw) * 16;
  }

  auto stage = [&](int jt, int buf) {
    const int jrow0 = jbase + jt * BJ;
    #pragma unroll
    for (int p = 0; p < 4; ++p) {
      const int rr = wave * 8 + p * 2;                     // wave-uniform local row pair
      const int lr = rr + (lane >> 5);                     // per-lane local row
      const int u  = (lane & 31) ^ (lr & 7);               // swizzled global 16B-chunk
      const unsigned char* gsrc = xq + (size_t)(jrow0 + lr) * ROWQ + u * 16;
      char* ldst = lds + buf * TILEB + rr * ROWQ;          // wave-uniform base
      __builtin_amdgcn_global_load_lds((const __attribute__((address_space(1))) void*)gsrc,
                                       (__attribute__((address_space(3))) void*)ldst,
                                       16, 0, 0);
    }
  };

  stage(0, 0);
  for (int jt = 0; jt < NTILES; ++jt) {
    __syncthreads();
    if (jt + 1 < NTILES) stage(jt + 1, (jt + 1) & 1);
    #pragma unroll
    for (int jh = 0; jh < 2; ++jh) {
      const char* brow = lds + (jt & 1) * TILEB + (jh * 16 + r16) * ROWQ;
      f32x4 acc0 = {0.f, 0.f, 0.f, 0.f};
      f32x4 acc1 = {0.f, 0.f, 0.f, 0.f};
      #pragma unroll
      for (int c = 0; c < 4; ++c) {
        i32x4 lo = *(const i32x4*)(brow + boff[2*c]);
        i32x4 hi = *(const i32x4*)(brow + boff[2*c+1]);
        i32x8 bf = i32x8{lo[0],lo[1],lo[2],lo[3],hi[0],hi[1],hi[2],hi[3]};
        acc0 = __builtin_amdgcn_mfma_scale_f32_16x16x128_f8f6f4(
                 a0[c], bf, acc0, 0, 0, 0, UNIT_SCALE, 0, UNIT_SCALE);
        acc1 = __builtin_amdgcn_mfma_scale_f32_16x16x128_f8f6f4(
                 a1[c], bf, acc1, 0, 0, 0, UNIT_SCALE, 0, UNIT_SCALE);
      }
      const int j = jbase + jt * BJ + jh * 16 + r16;
      const float sqj = sq[j];
      #pragma unroll
      for (int r = 0; r < 4; ++r) {
        float v0 = fmaf(-2.0f, acc0[r], sqj);
        v0 = fmaxf(v0, 0.0f);
        int u0 = (__builtin_bit_cast(int, v0) & KEYMASK) | j;
        kins(u0, m0[r], m1[r], m2[r]);
        float v1 = fmaf(-2.0f, acc1[r], sqj);
        v1 = fmaxf(v1, 0.0f);
        int u1 = (__builtin_bit_cast(int, v1) & KEYMASK) | j;
        kins(u1, m0[4+r], m1[4+r], m2[4+r]);
      }
    }
  }

  // ------- in-register butterfly merge across r16 (masks 1,2,4,8 stay in-quad) -------
  #pragma unroll
  for (int m = 1; m <= 8; m <<= 1) {
    #pragma unroll
    for (int q = 0; q < 8; ++q) {
      int o0 = __shfl_xor(m0[q], m, 64);
      int o1 = __shfl_xor(m1[q], m, 64);
      int o2 = __shfl_xor(m2[q], m, 64);
      kins(o0, m0[q], m1[q], m2[q]);
      kins(o1, m0[q], m1[q], m2[q]);
      kins(o2, m0[q], m1[q], m2[q]);
    }
  }

  // lane with r16 == q writes row q's merged packed top-3
  #pragma unroll
  for (int q = 0; q < 8; ++q) {
    if (r16 == q) {
      int s  = q >> 2, r = q & 3;
      int gi = ibase + s * 16 + quad * 4 + r;
      int ob = (gi * JGROUPS + bj) * 3;
      pk[ob + 0] = m0[q]; pk[ob + 1] = m1[q]; pk[ob + 2] = m2[q];
    }
  }
}

// ---------------- Kernel 3: merge partials, fp32 norms, hinge, mean ----------------
extern "C" __global__ __launch_bounds__(256)
void finalize_kernel(const float* __restrict__ x, const float* __restrict__ pos,
                     const int* __restrict__ pk, float* __restrict__ out) {
  __shared__ float wsum[4];
  int i    = blockIdx.x * 4 + (threadIdx.x >> 6);
  int wave = threadIdx.x >> 6;
  int lane = threadIdx.x & 63;
  int neg = 0;
  if (lane == 0) {
    int m0 = KEYINIT, m1 = KEYINIT, m2 = KEYINIT;
    #pragma unroll
    for (int s = 0; s < JGROUPS * 3; ++s) {
      kins(pk[i * (JGROUPS * 3) + s], m0, m1, m2);
    }
    neg = m2 & 0x3FFF;   // rank 2 (self is rank 0) == reference idx3[:,2]
  }
  neg = __shfl(neg, 0, 64);
  const float* xr = x   + (size_t)i * DD + lane * 8;
  const float* pr = pos + (size_t)i * DD + lane * 8;
  const float* nr = x   + (size_t)neg * DD + lane * 8;
  f32x4 xa = *(const f32x4*)xr, xb4 = *(const f32x4*)(xr + 4);
  f32x4 pa = *(const f32x4*)pr, pb  = *(const f32x4*)(pr + 4);
  f32x4 na = *(const f32x4*)nr, nb  = *(const f32x4*)(nr + 4);
  float sap = 0.f, san = 0.f;
  #pragma unroll
  for (int k = 0; k < 4; ++k) {
    float d0 = xa[k]  - pa[k] + EPSV; sap = fmaf(d0, d0, sap);
    float d1 = xa[k]  - na[k] + EPSV; san = fmaf(d1, d1, san);
    float d2 = xb4[k] - pb[k] + EPSV; sap = fmaf(d2, d2, sap);
    float d3 = xb4[k] - nb[k] + EPSV; san = fmaf(d3, d3, san);
  }
  #pragma unroll
  for (int off = 1; off < 64; off <<= 1) {
    sap += __shfl_xor(sap, off, 64);
    san += __shfl_xor(san, off, 64);
  }
  if (lane == 0) {
    float l = sqrtf(sap) - sqrtf(san) + MARGINV;
    wsum[wave] = l > 0.f ? l : 0.f;
  }
  __syncthreads();
  if (threadIdx.x == 0) {
    atomicAdd(out, (wsum[0] + wsum[1] + wsum[2] + wsum[3]) * (1.0f / NN));
  }
}

// ---------------- host ----------------
extern "C" void kernel_launch(void* const* d_in, const int* in_sizes, int n_in,
                              void* d_out, int out_size, void* d_ws, size_t ws_size,
                              hipStream_t stream) {
  const float* x   = (const float*)d_in[0];
  const float* pos = (const float*)d_in[1];
  char* ws = (char*)d_ws;
  unsigned char* xq = (unsigned char*)ws;                                 // 8 MB
  float* sq = (float*)(ws + (size_t)NN * ROWQ);                           // 64 KB
  int*   pk = (int*)  (ws + (size_t)NN * ROWQ + (size_t)NN * 4);          // 1.5 MB

  prep_kernel<<<NN / 4, 256, 0, stream>>>(x, xq, sq, (float*)d_out);
  knn_kernel<<<(NN / 128) * JGROUPS, 256, 0, stream>>>(xq, sq, pk);
  finalize_kernel<<<NN / 4, 256, 0, stream>>>(x, pos, pk, (float*)d_out);
}

// Round 6
// 289.825 us; speedup vs baseline: 2.8071x; 1.0061x over previous
//
#include <hip/hip_runtime.h>
#include <hip/hip_bf16.h>
#include <hip/hip_fp8.h>
#include <stdint.h>

#define NN 16384
#define DD 512
#define MARGINV 2.0f
#define EPSV 1e-6f

#define BJ 32
#define JGROUPS 6               // grid = 128 bi x 6 bj = 768 = exactly 3 blocks/CU resident
#define TOTTILES (NN / BJ)      // 512 tiles of 32 j, split unevenly 85/85/86/85/85/86
#define ROWQ 512                // fp8 row bytes
#define TILEB (BJ * ROWQ)       // 16384 B per tile buffer

#define KEYMASK 0xFFFFC000      // keep sign+exp+9 mantissa bits; low 14 = j (j<16384)
#define KEYINIT 0x7FFFFFFF
#define BIASV 640.0f            // > max sq_i: keys strictly positive, self provably rank 0

typedef __attribute__((ext_vector_type(4))) float f32x4;
typedef __attribute__((ext_vector_type(4))) int   i32x4;
typedef __attribute__((ext_vector_type(8))) int   i32x8;

#define UNIT_SCALE 0x7F   // E8M0 biased exponent 127 -> x1.0

__device__ inline int imin(int a, int b) { return a < b ? a : b; }
__device__ inline int imax(int a, int b) { return a > b ? a : b; }

// streaming insert of one packed key into a sorted-3 list (5 min/max ops)
__device__ inline void kins(int u, int& m0, int& m1, int& m2) {
  int t  = imax(m0, u); m0 = imin(m0, u);
  int t2 = imax(m1, t); m1 = imin(m1, t);
  m2 = imin(m2, t2);
}

// ---------------- Kernel 1: row sq-norms (fp32, +BIASV) + fp8 e4m3 quantize ----------------
extern "C" __global__ __launch_bounds__(256)
void prep_kernel(const float* __restrict__ x, unsigned char* __restrict__ xq,
                 float* __restrict__ sqb, float* __restrict__ out) {
  if (blockIdx.x == 0 && threadIdx.x == 0) out[0] = 0.0f;   // replaces memset dispatch
  int row  = blockIdx.x * 4 + (threadIdx.x >> 6);
  int lane = threadIdx.x & 63;
  const float* xr = x + (size_t)row * DD + lane * 8;
  f32x4 a = *(const f32x4*)xr;
  f32x4 b = *(const f32x4*)(xr + 4);
  float s = a[0]*a[0]+a[1]*a[1]+a[2]*a[2]+a[3]*a[3]
          + b[0]*b[0]+b[1]*b[1]+b[2]*b[2]+b[3]*b[3];
  #pragma unroll
  for (int off = 1; off < 64; off <<= 1) s += __shfl_xor(s, off, 64);
  unsigned long long pk = 0;
  #pragma unroll
  for (int t = 0; t < 4; ++t) {
    __hip_fp8_e4m3 qa(a[t]), qb(b[t]);
    pk |= ((unsigned long long)qa.__x) << (8 * t);
    pk |= ((unsigned long long)qb.__x) << (8 * (t + 4));
  }
  *(unsigned long long*)(xq + (size_t)row * ROWQ + lane * 8) = pk;
  // key value = sq[j] - 2*dot + BIASV  (per-i constant sq[i] omitted; +BIASV makes
  // every key positive: int-compare of float bits valid, self (= BIASV - sq_i) rank 0)
  if (lane == 0) sqb[row] = s + BIASV;
}

// ---------------- Kernel 2: fused MX-fp8 GEMM (X·X^T) + per-row packed top-3 -------------
// mfma_scale_f32_16x16x128_f8f6f4 (fp8 e4m3, unit scales == plain fp8 dot, 2x rate).
// block = 256 thr (4 waves) covers 128 i-rows x one j-group (85-86 tiles of 32 j).
// Per wave: 2 A-sets of 16 i-rows (64 regs); each 32-B B-fragment -> 2 MFMAs.
// Top-3 as packed int keys: (float_bits(d2val) & 0xFFFFC000) | j  (lowest-j tie-break
// == lax.top_k order; self provably rank 0 via +BIASV) -> rank 2 == idx3[:,2].
// ~148 unified regs/wave -> 3 waves/SIMD; grid 768 = 3 blocks/CU resident, ZERO tail.
extern "C" __global__ __launch_bounds__(256, 3)
void knn_kernel(const unsigned char* __restrict__ xq, const float* __restrict__ sqb,
                int* __restrict__ pk) {
  __shared__ __align__(16) char lds[2 * TILEB];  // 32,768 B
  const int tid  = threadIdx.x;
  const int wave = tid >> 6;
  const int lane = tid & 63;
  const int quad = lane >> 4;
  const int r16  = lane & 15;
  const int bi   = blockIdx.x / JGROUPS;        // 0..127
  const int bj   = blockIdx.x % JGROUPS;        // 0..5
  const int ibase  = bi * 128 + wave * 32;      // 32 i-rows per wave
  const int tstart = (TOTTILES * bj) / JGROUPS;       // uneven split: 0,85,170,256,341,426
  const int tend   = (TOTTILES * (bj + 1)) / JGROUPS;
  const int ntiles = tend - tstart;             // 85 or 86
  const int jbase  = tstart * BJ;

  // A fragments: 2 sets x 4 k-chunks x 32 B (v8i32). A[m=r16][k=chunk*128+quad*32+t]
  i32x8 a0[4], a1[4];
  {
    const unsigned char* ar0 = xq + (size_t)(ibase + r16)      * ROWQ + quad * 32;
    const unsigned char* ar1 = xq + (size_t)(ibase + 16 + r16) * ROWQ + quad * 32;
    #pragma unroll
    for (int c = 0; c < 4; ++c) {
      i32x4 lo0 = *(const i32x4*)(ar0 + c * 128);
      i32x4 hi0 = *(const i32x4*)(ar0 + c * 128 + 16);
      i32x4 lo1 = *(const i32x4*)(ar1 + c * 128);
      i32x4 hi1 = *(const i32x4*)(ar1 + c * 128 + 16);
      a0[c] = i32x8{lo0[0],lo0[1],lo0[2],lo0[3],hi0[0],hi0[1],hi0[2],hi0[3]};
      a1[c] = i32x8{lo1[0],lo1[1],lo1[2],lo1[3],hi1[0],hi1[1],hi1[2],hi1[3]};
    }
  }

  // packed top-3 per (set s, reg r): q = s*4 + r; i-row = ibase + s*16 + quad*4 + r
  int m0[8], m1[8], m2[8];
  #pragma unroll
  for (int q = 0; q < 8; ++q) { m0[q] = m1[q] = m2[q] = KEYINIT; }

  // jt-invariant swizzled B chunk offsets
  const int sw = r16 & 7;
  int boff[8];
  #pragma unroll
  for (int c = 0; c < 4; ++c) {
    const int g0 = c * 8 + quad * 2;
    boff[2*c]   = (g0       ^ sw) * 16;
    boff[2*c+1] = ((g0 + 1) ^ sw) * 16;
  }

  auto stage = [&](int jt, int buf) {
    const int jrow0 = jbase + jt * BJ;
    #pragma unroll
    for (int p = 0; p < 4; ++p) {
      const int rr = wave * 8 + p * 2;                     // wave-uniform local row pair
      const int lr = rr + (lane >> 5);                     // per-lane local row
      const int u  = (lane & 31) ^ (lr & 7);               // swizzled global 16B-chunk
      const unsigned char* gsrc = xq + (size_t)(jrow0 + lr) * ROWQ + u * 16;
      char* ldst = lds + buf * TILEB + rr * ROWQ;          // wave-uniform base
      __builtin_amdgcn_global_load_lds((const __attribute__((address_space(1))) void*)gsrc,
                                       (__attribute__((address_space(3))) void*)ldst,
                                       16, 0, 0);
    }
  };

  stage(0, 0);
  for (int jt = 0; jt < ntiles; ++jt) {
    __syncthreads();
    if (jt + 1 < ntiles) stage(jt + 1, (jt + 1) & 1);
    #pragma unroll
    for (int jh = 0; jh < 2; ++jh) {
      const char* brow = lds + (jt & 1) * TILEB + (jh * 16 + r16) * ROWQ;
      f32x4 acc0 = {0.f, 0.f, 0.f, 0.f};
      f32x4 acc1 = {0.f, 0.f, 0.f, 0.f};
      #pragma unroll
      for (int c = 0; c < 4; ++c) {
        i32x4 lo = *(const i32x4*)(brow + boff[2*c]);
        i32x4 hi = *(const i32x4*)(brow + boff[2*c+1]);
        i32x8 bf = i32x8{lo[0],lo[1],lo[2],lo[3],hi[0],hi[1],hi[2],hi[3]};
        acc0 = __builtin_amdgcn_mfma_scale_f32_16x16x128_f8f6f4(
                 a0[c], bf, acc0, 0, 0, 0, UNIT_SCALE, 0, UNIT_SCALE);
        acc1 = __builtin_amdgcn_mfma_scale_f32_16x16x128_f8f6f4(
                 a1[c], bf, acc1, 0, 0, 0, UNIT_SCALE, 0, UNIT_SCALE);
      }
      const int j = jbase + jt * BJ + jh * 16 + r16;
      const float sqj = sqb[j];
      #pragma unroll
      for (int r = 0; r < 4; ++r) {
        float v0 = fmaf(-2.0f, acc0[r], sqj);              // > 0 by BIASV construction
        int u0 = (__builtin_bit_cast(int, v0) & KEYMASK) | j;
        kins(u0, m0[r], m1[r], m2[r]);
        float v1 = fmaf(-2.0f, acc1[r], sqj);
        int u1 = (__builtin_bit_cast(int, v1) & KEYMASK) | j;
        kins(u1, m0[4+r], m1[4+r], m2[4+r]);
      }
    }
  }

  // ------- in-register butterfly merge across r16 (masks 1,2,4,8 stay in-quad) -------
  #pragma unroll
  for (int m = 1; m <= 8; m <<= 1) {
    #pragma unroll
    for (int q = 0; q < 8; ++q) {
      int o0 = __shfl_xor(m0[q], m, 64);
      int o1 = __shfl_xor(m1[q], m, 64);
      int o2 = __shfl_xor(m2[q], m, 64);
      kins(o0, m0[q], m1[q], m2[q]);
      kins(o1, m0[q], m1[q], m2[q]);
      kins(o2, m0[q], m1[q], m2[q]);
    }
  }

  // lane with r16 == q writes row q's merged packed top-3
  #pragma unroll
  for (int q = 0; q < 8; ++q) {
    if (r16 == q) {
      int s  = q >> 2, r = q & 3;
      int gi = ibase + s * 16 + quad * 4 + r;
      int ob = (gi * JGROUPS + bj) * 3;
      pk[ob + 0] = m0[q]; pk[ob + 1] = m1[q]; pk[ob + 2] = m2[q];
    }
  }
}

// ---------------- Kernel 3: merge partials, fp32 norms, hinge, mean ----------------
extern "C" __global__ __launch_bounds__(256)
void finalize_kernel(const float* __restrict__ x, const float* __restrict__ pos,
                     const int* __restrict__ pk, float* __restrict__ out) {
  __shared__ float wsum[4];
  int i    = blockIdx.x * 4 + (threadIdx.x >> 6);
  int wave = threadIdx.x >> 6;
  int lane = threadIdx.x & 63;
  int neg = 0;
  if (lane == 0) {
    int m0 = KEYINIT, m1 = KEYINIT, m2 = KEYINIT;
    #pragma unroll
    for (int s = 0; s < JGROUPS * 3; ++s) {
      kins(pk[i * (JGROUPS * 3) + s], m0, m1, m2);
    }
    neg = m2 & 0x3FFF;   // rank 2 (self is rank 0) == reference idx3[:,2]
  }
  neg = __shfl(neg, 0, 64);
  const float* xr = x   + (size_t)i * DD + lane * 8;
  const float* pr = pos + (size_t)i * DD + lane * 8;
  const float* nr = x   + (size_t)neg * DD + lane * 8;
  f32x4 xa = *(const f32x4*)xr, xb4 = *(const f32x4*)(xr + 4);
  f32x4 pa = *(const f32x4*)pr, pb  = *(const f32x4*)(pr + 4);
  f32x4 na = *(const f32x4*)nr, nb  = *(const f32x4*)(nr + 4);
  float sap = 0.f, san = 0.f;
  #pragma unroll
  for (int k = 0; k < 4; ++k) {
    float d0 = xa[k]  - pa[k] + EPSV; sap = fmaf(d0, d0, sap);
    float d1 = xa[k]  - na[k] + EPSV; san = fmaf(d1, d1, san);
    float d2 = xb4[k] - pb[k] + EPSV; sap = fmaf(d2, d2, sap);
    float d3 = xb4[k] - nb[k] + EPSV; san = fmaf(d3, d3, san);
  }
  #pragma unroll
  for (int off = 1; off < 64; off <<= 1) {
    sap += __shfl_xor(sap, off, 64);
    san += __shfl_xor(san, off, 64);
  }
  if (lane == 0) {
    float l = sqrtf(sap) - sqrtf(san) + MARGINV;
    wsum[wave] = l > 0.f ? l : 0.f;
  }
  __syncthreads();
  if (threadIdx.x == 0) {
    atomicAdd(out, (wsum[0] + wsum[1] + wsum[2] + wsum[3]) * (1.0f / NN));
  }
}

// ---------------- host ----------------
extern "C" void kernel_launch(void* const* d_in, const int* in_sizes, int n_in,
                              void* d_out, int out_size, void* d_ws, size_t ws_size,
                              hipStream_t stream) {
  const float* x   = (const float*)d_in[0];
  const float* pos = (const float*)d_in[1];
  char* ws = (char*)d_ws;
  unsigned char* xq  = (unsigned char*)ws;                                // 8 MB
  float* sqb = (float*)(ws + (size_t)NN * ROWQ);                          // 64 KB
  int*   pk  = (int*)  (ws + (size_t)NN * ROWQ + (size_t)NN * 4);         // 1.2 MB

  prep_kernel<<<NN / 4, 256, 0, stream>>>(x, xq, sqb, (float*)d_out);
  knn_kernel<<<(NN / 128) * JGROUPS, 256, 0, stream>>>(xq, sqb, pk);
  finalize_kernel<<<NN / 4, 256, 0, stream>>>(x, pos, pk, (float*)d_out);
}

// Round 7
// 278.941 us; speedup vs baseline: 2.9167x; 1.0390x over previous
//
#include <hip/hip_runtime.h>
#include <hip/hip_bf16.h>
#include <hip/hip_fp8.h>
#include <stdint.h>

#define NN 16384
#define DD 512
#define MARGINV 2.0f
#define EPSV 1e-6f

#define BJ 32
#define JGROUPS 8               // grid = 64 bi x 8 bj = 512 = exactly 2 blocks/CU, zero tail
#define JRANGE (NN / JGROUPS)   // 2048
#define NTILES (JRANGE / BJ)    // 64
#define ROWQ 512                // fp8 row bytes
#define TILEB (BJ * ROWQ)       // 16384 B per tile buffer

#define KEYMASK  0xFFFFC000     // keep sign+exp+9 mantissa bits; low 14 = j (j<16384)
#define KEYINITF __builtin_bit_cast(float, 0x7F000000)   // big positive finite float
#define BIASV 640.0f            // > max sq_i: keys strictly positive, self provably rank 0

typedef __attribute__((ext_vector_type(4))) float f32x4;
typedef __attribute__((ext_vector_type(4))) int   i32x4;
typedef __attribute__((ext_vector_type(8))) int   i32x8;

#define UNIT_SCALE 0x7F   // E8M0 biased exponent 127 -> x1.0

// sorted-3 insert via med3 (keys are positive finite floats; float order == int order)
// m2 first (uses old m1), then m1, then m0 — 3 VALU ops total.
__device__ inline void kins3f(float u, float& m0, float& m1, float& m2) {
  m2 = __builtin_amdgcn_fmed3f(m1, m2, u);
  m1 = __builtin_amdgcn_fmed3f(m0, m1, u);
  m0 = fminf(m0, u);
}

// ---------------- Kernel 1: row sq-norms (fp32, +BIASV) + fp8 e4m3 quantize ----------------
extern "C" __global__ __launch_bounds__(256)
void prep_kernel(const float* __restrict__ x, unsigned char* __restrict__ xq,
                 float* __restrict__ sqb, float* __restrict__ out) {
  if (blockIdx.x == 0 && threadIdx.x == 0) out[0] = 0.0f;   // replaces memset dispatch
  int row  = blockIdx.x * 4 + (threadIdx.x >> 6);
  int lane = threadIdx.x & 63;
  const float* xr = x + (size_t)row * DD + lane * 8;
  f32x4 a = *(const f32x4*)xr;
  f32x4 b = *(const f32x4*)(xr + 4);
  float s = a[0]*a[0]+a[1]*a[1]+a[2]*a[2]+a[3]*a[3]
          + b[0]*b[0]+b[1]*b[1]+b[2]*b[2]+b[3]*b[3];
  #pragma unroll
  for (int off = 1; off < 64; off <<= 1) s += __shfl_xor(s, off, 64);
  unsigned long long pk = 0;
  #pragma unroll
  for (int t = 0; t < 4; ++t) {
    __hip_fp8_e4m3 qa(a[t]), qb(b[t]);
    pk |= ((unsigned long long)qa.__x) << (8 * t);
    pk |= ((unsigned long long)qb.__x) << (8 * (t + 4));
  }
  *(unsigned long long*)(xq + (size_t)row * ROWQ + lane * 8) = pk;
  // key value = sq[j] - 2*dot + BIASV: strictly positive, self (BIASV - sq_i) rank 0
  if (lane == 0) sqb[row] = s + BIASV;
}

// ---------------- Kernel 2: fused MX-fp8 GEMM (X·X^T) + per-row packed top-3 -------------
// mfma_scale_f32_16x16x128_f8f6f4 (fp8 e4m3, unit scales == plain fp8 dot, 2x rate).
// block = 256 thr (4 waves) covers 256 i-rows x one j-group of 2048 (64 tiles of 32 j).
// Per wave: FOUR A-sets of 16 i-rows (128 VGPR) -> each 32-B B-fragment feeds 4 MFMAs
// (LDS traffic halved vs round 6: the binding pipe).
// Swizzle restricted to even bits (sw = r16 & 6): 16B-chunk pairs stay adjacent+ordered
// -> direct i32x8 LDS load (2x ds_read_b128, consecutive regs, no concat movs).
// Top-3 packed keys (float_bits & 0xFFFFC000) | j, med3-based 3-op insert.
// ~225 unified regs -> 2 waves/SIMD; grid 512 = 2 blocks/CU, zero tail.
extern "C" __global__ __launch_bounds__(256, 2)
void knn_kernel(const unsigned char* __restrict__ xq, const float* __restrict__ sqb,
                int* __restrict__ pk) {
  __shared__ __align__(16) char lds[2 * TILEB];  // 32,768 B
  const int tid  = threadIdx.x;
  const int wave = tid >> 6;
  const int lane = tid & 63;
  const int quad = lane >> 4;
  const int r16  = lane & 15;
  const int bi   = blockIdx.x >> 3;             // 0..63
  const int bj   = blockIdx.x & 7;              // 0..7
  const int ibase = bi * 256 + wave * 64;       // 64 i-rows per wave
  const int jbase = bj * JRANGE;

  // A fragments: 4 sets x 4 k-chunks x 32 B (v8i32). A[m=r16][k=chunk*128+quad*32+t]
  i32x8 afr[4][4];
  #pragma unroll
  for (int s = 0; s < 4; ++s) {
    const unsigned char* ar = xq + (size_t)(ibase + s * 16 + r16) * ROWQ + quad * 32;
    #pragma unroll
    for (int c = 0; c < 4; ++c)
      afr[s][c] = *(const i32x8*)(ar + c * 128);   // 32B-aligned: 2x ds.. global dwordx4
  }

  // packed top-3 per (set s, reg r): q = s*4 + r; i-row = ibase + s*16 + quad*4 + r
  float m0[16], m1[16], m2[16];
  #pragma unroll
  for (int q = 0; q < 16; ++q) { m0[q] = m1[q] = m2[q] = KEYINITF; }

  auto stage = [&](int jt, int buf) {
    const int jrow0 = jbase + jt * BJ;
    #pragma unroll
    for (int p = 0; p < 4; ++p) {
      const int rr = wave * 8 + p * 2;                     // wave-uniform local row pair
      const int lr = rr + (lane >> 5);                     // per-lane local row
      const int u  = (lane & 31) ^ (lr & 6);               // EVEN-bit swizzle only
      const unsigned char* gsrc = xq + (size_t)(jrow0 + lr) * ROWQ + u * 16;
      char* ldst = lds + buf * TILEB + rr * ROWQ;          // wave-uniform base
      __builtin_amdgcn_global_load_lds((const __attribute__((address_space(1))) void*)gsrc,
                                       (__attribute__((address_space(3))) void*)ldst,
                                       16, 0, 0);
    }
  };

  const int sw = r16 & 6;
  stage(0, 0);
  for (int jt = 0; jt < NTILES; ++jt) {
    __syncthreads();
    if (jt + 1 < NTILES) stage(jt + 1, (jt + 1) & 1);
    #pragma unroll
    for (int jh = 0; jh < 2; ++jh) {
      const char* brow = lds + (jt & 1) * TILEB + (jh * 16 + r16) * ROWQ;
      f32x4 acc[4] = {{0.f,0.f,0.f,0.f},{0.f,0.f,0.f,0.f},
                      {0.f,0.f,0.f,0.f},{0.f,0.f,0.f,0.f}};
      #pragma unroll
      for (int c = 0; c < 4; ++c) {
        // sw even, g0 even -> (g0^sw, g0+1^sw) adjacent & in order: one 32B LDS read
        i32x8 bf = *(const i32x8*)(brow + (((c * 8 + quad * 2) ^ sw) * 16));
        #pragma unroll
        for (int s = 0; s < 4; ++s)
          acc[s] = __builtin_amdgcn_mfma_scale_f32_16x16x128_f8f6f4(
                     afr[s][c], bf, acc[s], 0, 0, 0, UNIT_SCALE, 0, UNIT_SCALE);
      }
      const int j = jbase + jt * BJ + jh * 16 + r16;
      const float sqj = sqb[j];
      const float fj  = __builtin_bit_cast(float, j);      // j fits in low 14 bits
      #pragma unroll
      for (int s = 0; s < 4; ++s) {
        #pragma unroll
        for (int r = 0; r < 4; ++r) {
          float v = fmaf(-2.0f, acc[s][r], sqj);           // > 0 by BIASV construction
          int   b = (__builtin_bit_cast(int, v) & KEYMASK) | j;   // v_and_or_b32
          kins3f(__builtin_bit_cast(float, b), m0[s*4+r], m1[s*4+r], m2[s*4+r]);
        }
      }
      (void)fj;
    }
  }

  // ------- in-register butterfly merge across r16 (masks 1,2,4,8 stay in-quad) -------
  #pragma unroll
  for (int m = 1; m <= 8; m <<= 1) {
    #pragma unroll
    for (int q = 0; q < 16; ++q) {
      float o0 = __shfl_xor(m0[q], m, 64);
      float o1 = __shfl_xor(m1[q], m, 64);
      float o2 = __shfl_xor(m2[q], m, 64);
      kins3f(o0, m0[q], m1[q], m2[q]);
      kins3f(o1, m0[q], m1[q], m2[q]);
      kins3f(o2, m0[q], m1[q], m2[q]);
    }
  }

  // lane with r16 == q writes row q's merged packed top-3 (16 writers x 4 quads)
  #pragma unroll
  for (int q = 0; q < 16; ++q) {
    if (r16 == q) {
      int s  = q >> 2, r = q & 3;
      int gi = ibase + s * 16 + quad * 4 + r;
      int ob = (gi * JGROUPS + bj) * 3;
      pk[ob + 0] = __builtin_bit_cast(int, m0[q]);
      pk[ob + 1] = __builtin_bit_cast(int, m1[q]);
      pk[ob + 2] = __builtin_bit_cast(int, m2[q]);
    }
  }
}

// ---------------- Kernel 3: merge partials, fp32 norms, hinge, mean ----------------
extern "C" __global__ __launch_bounds__(256)
void finalize_kernel(const float* __restrict__ x, const float* __restrict__ pos,
                     const int* __restrict__ pk, float* __restrict__ out) {
  __shared__ float wsum[4];
  int i    = blockIdx.x * 4 + (threadIdx.x >> 6);
  int wave = threadIdx.x >> 6;
  int lane = threadIdx.x & 63;
  int neg = 0;
  if (lane == 0) {
    float m0 = KEYINITF, m1 = KEYINITF, m2 = KEYINITF;
    #pragma unroll
    for (int s = 0; s < JGROUPS * 3; ++s) {
      kins3f(__builtin_bit_cast(float, pk[i * (JGROUPS * 3) + s]), m0, m1, m2);
    }
    neg = __builtin_bit_cast(int, m2) & 0x3FFF;  // rank 2 (self rank 0) == idx3[:,2]
  }
  neg = __shfl(neg, 0, 64);
  const float* xr = x   + (size_t)i * DD + lane * 8;
  const float* pr = pos + (size_t)i * DD + lane * 8;
  const float* nr = x   + (size_t)neg * DD + lane * 8;
  f32x4 xa = *(const f32x4*)xr, xb4 = *(const f32x4*)(xr + 4);
  f32x4 pa = *(const f32x4*)pr, pb  = *(const f32x4*)(pr + 4);
  f32x4 na = *(const f32x4*)nr, nb  = *(const f32x4*)(nr + 4);
  float sap = 0.f, san = 0.f;
  #pragma unroll
  for (int k = 0; k < 4; ++k) {
    float d0 = xa[k]  - pa[k] + EPSV; sap = fmaf(d0, d0, sap);
    float d1 = xa[k]  - na[k] + EPSV; san = fmaf(d1, d1, san);
    float d2 = xb4[k] - pb[k] + EPSV; sap = fmaf(d2, d2, sap);
    float d3 = xb4[k] - nb[k] + EPSV; san = fmaf(d3, d3, san);
  }
  #pragma unroll
  for (int off = 1; off < 64; off <<= 1) {
    sap += __shfl_xor(sap, off, 64);
    san += __shfl_xor(san, off, 64);
  }
  if (lane == 0) {
    float l = sqrtf(sap) - sqrtf(san) + MARGINV;
    wsum[wave] = l > 0.f ? l : 0.f;
  }
  __syncthreads();
  if (threadIdx.x == 0) {
    atomicAdd(out, (wsum[0] + wsum[1] + wsum[2] + wsum[3]) * (1.0f / NN));
  }
}

// ---------------- host ----------------
extern "C" void kernel_launch(void* const* d_in, const int* in_sizes, int n_in,
                              void* d_out, int out_size, void* d_ws, size_t ws_size,
                              hipStream_t stream) {
  const float* x   = (const float*)d_in[0];
  const float* pos = (const float*)d_in[1];
  char* ws = (char*)d_ws;
  unsigned char* xq  = (unsigned char*)ws;                                // 8 MB
  float* sqb = (float*)(ws + (size_t)NN * ROWQ);                          // 64 KB
  int*   pk  = (int*)  (ws + (size_t)NN * ROWQ + (size_t)NN * 4);         // 1.5 MB

  prep_kernel<<<NN / 4, 256, 0, stream>>>(x, xq, sqb, (float*)d_out);
  knn_kernel<<<(NN / 256) * JGROUPS, 256, 0, stream>>>(xq, sqb, pk);
  finalize_kernel<<<NN / 4, 256, 0, stream>>>(x, pos, pk, (float*)d_out);
}

// Round 8
// 273.940 us; speedup vs baseline: 2.9699x; 1.0183x over previous
//
#include <hip/hip_runtime.h>
#include <hip/hip_bf16.h>
#include <hip/hip_fp8.h>
#include <stdint.h>

#define NN 16384
#define DD 512
#define MARGINV 2.0f
#define EPSV 1e-6f

#define BJ 32
#define JGROUPS 8               // grid = 64 bi x 8 bj = 512 = exactly 2 blocks/CU, zero tail
#define JRANGE (NN / JGROUPS)   // 2048
#define NTILES (JRANGE / BJ)    // 64
#define ROWQ 512                // fp8 row bytes
#define TILEB (BJ * ROWQ)       // 16384 B per tile buffer

#define KEYMASK  0xFFFFC000     // keep sign+exp+9 mantissa bits; low 14 = j (j<16384)
#define KEYINITF __builtin_bit_cast(float, 0x7F000000)   // big positive finite float
#define BIASV 640.0f            // > max sq_i: keys strictly positive, self provably rank 0

typedef __attribute__((ext_vector_type(4))) float f32x4;
typedef __attribute__((ext_vector_type(4))) int   i32x4;
typedef __attribute__((ext_vector_type(8))) int   i32x8;

#define UNIT_SCALE 0x7F   // E8M0 biased exponent 127 -> x1.0

// sorted-3 insert via med3 (keys are positive finite floats; float order == int order)
__device__ inline void kins3f(float u, float& m0, float& m1, float& m2) {
  m2 = __builtin_amdgcn_fmed3f(m1, m2, u);
  m1 = __builtin_amdgcn_fmed3f(m0, m1, u);
  m0 = fminf(m0, u);
}

// ---------------- Kernel 1: row sq-norms (fp32, +BIASV) + fp8 e4m3 quantize ----------------
extern "C" __global__ __launch_bounds__(256)
void prep_kernel(const float* __restrict__ x, unsigned char* __restrict__ xq,
                 float* __restrict__ sqb, float* __restrict__ out) {
  if (blockIdx.x == 0 && threadIdx.x == 0) out[0] = 0.0f;   // replaces memset dispatch
  int row  = blockIdx.x * 4 + (threadIdx.x >> 6);
  int lane = threadIdx.x & 63;
  const float* xr = x + (size_t)row * DD + lane * 8;
  f32x4 a = *(const f32x4*)xr;
  f32x4 b = *(const f32x4*)(xr + 4);
  float s = a[0]*a[0]+a[1]*a[1]+a[2]*a[2]+a[3]*a[3]
          + b[0]*b[0]+b[1]*b[1]+b[2]*b[2]+b[3]*b[3];
  #pragma unroll
  for (int off = 1; off < 64; off <<= 1) s += __shfl_xor(s, off, 64);
  unsigned long long pk = 0;
  #pragma unroll
  for (int t = 0; t < 4; ++t) {
    __hip_fp8_e4m3 qa(a[t]), qb(b[t]);
    pk |= ((unsigned long long)qa.__x) << (8 * t);
    pk |= ((unsigned long long)qb.__x) << (8 * (t + 4));
  }
  *(unsigned long long*)(xq + (size_t)row * ROWQ + lane * 8) = pk;
  // key value = sq[j] - 2*dot + BIASV: strictly positive, self (BIASV - sq_i) rank 0
  if (lane == 0) sqb[row] = s + BIASV;
}

// ---------------- Kernel 2: fused MX-fp8 GEMM (X·X^T) + per-row packed top-3 -------------
// mfma_scale_f32_16x16x128_f8f6f4 (fp8 e4m3, unit scales == plain fp8 dot, 2x rate).
// block = 256 thr (4 waves) covers 256 i-rows x one j-group of 2048 (64 tiles of 32 j).
// Per wave: FOUR A-sets of 16 i-rows (128 regs) -> each 32-B B-fragment feeds 4 MFMAs.
// FULL 3-bit 16B-chunk XOR swizzle (sw = r16 & 7): row stride 512 ≡ 0 mod 32 banks, so
// bank group = chunk mod 8 -- full swizzle spreads each b128 across all 8 groups
// (round-7's even-bit swizzle hit only even groups -> 2x conflict serialization).
// B = two ds_read_b128 + register concat (concat movs measured free: r6 vs r7 VALUBusy).
// Top-3 packed keys (float_bits & 0xFFFFC000) | j, med3 3-op insert.
extern "C" __global__ __launch_bounds__(256, 2)
void knn_kernel(const unsigned char* __restrict__ xq, const float* __restrict__ sqb,
                int* __restrict__ pk) {
  __shared__ __align__(16) char lds[2 * TILEB];  // 32,768 B
  const int tid  = threadIdx.x;
  const int wave = tid >> 6;
  const int lane = tid & 63;
  const int quad = lane >> 4;
  const int r16  = lane & 15;
  const int bi   = blockIdx.x >> 3;             // 0..63
  const int bj   = blockIdx.x & 7;              // 0..7
  const int ibase = bi * 256 + wave * 64;       // 64 i-rows per wave
  const int jbase = bj * JRANGE;

  // A fragments: 4 sets x 4 k-chunks x 32 B (v8i32). A[m=r16][k=chunk*128+quad*32+t]
  i32x8 afr[4][4];
  #pragma unroll
  for (int s = 0; s < 4; ++s) {
    const unsigned char* ar = xq + (size_t)(ibase + s * 16 + r16) * ROWQ + quad * 32;
    #pragma unroll
    for (int c = 0; c < 4; ++c)
      afr[s][c] = *(const i32x8*)(ar + c * 128);
  }

  // packed top-3 per (set s, reg r): q = s*4 + r; i-row = ibase + s*16 + quad*4 + r
  float m0[16], m1[16], m2[16];
  #pragma unroll
  for (int q = 0; q < 16; ++q) { m0[q] = m1[q] = m2[q] = KEYINITF; }

  auto stage = [&](int jt, int buf) {
    const int jrow0 = jbase + jt * BJ;
    #pragma unroll
    for (int p = 0; p < 4; ++p) {
      const int rr = wave * 8 + p * 2;                     // wave-uniform local row pair
      const int lr = rr + (lane >> 5);                     // per-lane local row
      const int u  = (lane & 31) ^ (lr & 7);               // FULL 3-bit swizzle
      const unsigned char* gsrc = xq + (size_t)(jrow0 + lr) * ROWQ + u * 16;
      char* ldst = lds + buf * TILEB + rr * ROWQ;          // wave-uniform base
      __builtin_amdgcn_global_load_lds((const __attribute__((address_space(1))) void*)gsrc,
                                       (__attribute__((address_space(3))) void*)ldst,
                                       16, 0, 0);
    }
  };

  const int sw = r16 & 7;
  stage(0, 0);
  for (int jt = 0; jt < NTILES; ++jt) {
    __syncthreads();
    if (jt + 1 < NTILES) stage(jt + 1, (jt + 1) & 1);
    #pragma unroll
    for (int jh = 0; jh < 2; ++jh) {
      const char* brow = lds + (jt & 1) * TILEB + (jh * 16 + r16) * ROWQ;
      f32x4 acc[4] = {{0.f,0.f,0.f,0.f},{0.f,0.f,0.f,0.f},
                      {0.f,0.f,0.f,0.f},{0.f,0.f,0.f,0.f}};
      #pragma unroll
      for (int c = 0; c < 4; ++c) {
        const int g0 = c * 8 + quad * 2;
        i32x4 lo = *(const i32x4*)(brow + ((g0       ^ sw) * 16));
        i32x4 hi = *(const i32x4*)(brow + (((g0 + 1) ^ sw) * 16));
        i32x8 bf = i32x8{lo[0],lo[1],lo[2],lo[3],hi[0],hi[1],hi[2],hi[3]};
        #pragma unroll
        for (int s = 0; s < 4; ++s)
          acc[s] = __builtin_amdgcn_mfma_scale_f32_16x16x128_f8f6f4(
                     afr[s][c], bf, acc[s], 0, 0, 0, UNIT_SCALE, 0, UNIT_SCALE);
      }
      const int j = jbase + jt * BJ + jh * 16 + r16;
      const float sqj = sqb[j];
      #pragma unroll
      for (int s = 0; s < 4; ++s) {
        #pragma unroll
        for (int r = 0; r < 4; ++r) {
          float v = fmaf(-2.0f, acc[s][r], sqj);           // > 0 by BIASV construction
          int   b = (__builtin_bit_cast(int, v) & KEYMASK) | j;   // v_and_or_b32
          kins3f(__builtin_bit_cast(float, b), m0[s*4+r], m1[s*4+r], m2[s*4+r]);
        }
      }
    }
  }

  // ------- in-register butterfly merge across r16 (masks 1,2,4,8 stay in-quad) -------
  #pragma unroll
  for (int m = 1; m <= 8; m <<= 1) {
    #pragma unroll
    for (int q = 0; q < 16; ++q) {
      float o0 = __shfl_xor(m0[q], m, 64);
      float o1 = __shfl_xor(m1[q], m, 64);
      float o2 = __shfl_xor(m2[q], m, 64);
      kins3f(o0, m0[q], m1[q], m2[q]);
      kins3f(o1, m0[q], m1[q], m2[q]);
      kins3f(o2, m0[q], m1[q], m2[q]);
    }
  }

  // lane with r16 == q writes row q's merged packed top-3 (16 writers x 4 quads)
  #pragma unroll
  for (int q = 0; q < 16; ++q) {
    if (r16 == q) {
      int s  = q >> 2, r = q & 3;
      int gi = ibase + s * 16 + quad * 4 + r;
      int ob = (gi * JGROUPS + bj) * 3;
      pk[ob + 0] = __builtin_bit_cast(int, m0[q]);
      pk[ob + 1] = __builtin_bit_cast(int, m1[q]);
      pk[ob + 2] = __builtin_bit_cast(int, m2[q]);
    }
  }
}

// ---------------- Kernel 3: merge partials, fp32 norms, hinge, mean ----------------
extern "C" __global__ __launch_bounds__(256)
void finalize_kernel(const float* __restrict__ x, const float* __restrict__ pos,
                     const int* __restrict__ pk, float* __restrict__ out) {
  __shared__ float wsum[4];
  int i    = blockIdx.x * 4 + (threadIdx.x >> 6);
  int wave = threadIdx.x >> 6;
  int lane = threadIdx.x & 63;
  int neg = 0;
  if (lane == 0) {
    float m0 = KEYINITF, m1 = KEYINITF, m2 = KEYINITF;
    #pragma unroll
    for (int s = 0; s < JGROUPS * 3; ++s) {
      kins3f(__builtin_bit_cast(float, pk[i * (JGROUPS * 3) + s]), m0, m1, m2);
    }
    neg = __builtin_bit_cast(int, m2) & 0x3FFF;  // rank 2 (self rank 0) == idx3[:,2]
  }
  neg = __shfl(neg, 0, 64);
  const float* xr = x   + (size_t)i * DD + lane * 8;
  const float* pr = pos + (size_t)i * DD + lane * 8;
  const float* nr = x   + (size_t)neg * DD + lane * 8;
  f32x4 xa = *(const f32x4*)xr, xb4 = *(const f32x4*)(xr + 4);
  f32x4 pa = *(const f32x4*)pr, pb  = *(const f32x4*)(pr + 4);
  f32x4 na = *(const f32x4*)nr, nb  = *(const f32x4*)(nr + 4);
  float sap = 0.f, san = 0.f;
  #pragma unroll
  for (int k = 0; k < 4; ++k) {
    float d0 = xa[k]  - pa[k] + EPSV; sap = fmaf(d0, d0, sap);
    float d1 = xa[k]  - na[k] + EPSV; san = fmaf(d1, d1, san);
    float d2 = xb4[k] - pb[k] + EPSV; sap = fmaf(d2, d2, sap);
    float d3 = xb4[k] - nb[k] + EPSV; san = fmaf(d3, d3, san);
  }
  #pragma unroll
  for (int off = 1; off < 64; off <<= 1) {
    sap += __shfl_xor(sap, off, 64);
    san += __shfl_xor(san, off, 64);
  }
  if (lane == 0) {
    float l = sqrtf(sap) - sqrtf(san) + MARGINV;
    wsum[wave] = l > 0.f ? l : 0.f;
  }
  __syncthreads();
  if (threadIdx.x == 0) {
    atomicAdd(out, (wsum[0] + wsum[1] + wsum[2] + wsum[3]) * (1.0f / NN));
  }
}

// ---------------- host ----------------
extern "C" void kernel_launch(void* const* d_in, const int* in_sizes, int n_in,
                              void* d_out, int out_size, void* d_ws, size_t ws_size,
                              hipStream_t stream) {
  const float* x   = (const float*)d_in[0];
  const float* pos = (const float*)d_in[1];
  char* ws = (char*)d_ws;
  unsigned char* xq  = (unsigned char*)ws;                                // 8 MB
  float* sqb = (float*)(ws + (size_t)NN * ROWQ);                          // 64 KB
  int*   pk  = (int*)  (ws + (size_t)NN * ROWQ + (size_t)NN * 4);         // 1.5 MB

  prep_kernel<<<NN / 4, 256, 0, stream>>>(x, xq, sqb, (float*)d_out);
  knn_kernel<<<(NN / 256) * JGROUPS, 256, 0, stream>>>(xq, sqb, pk);
  finalize_kernel<<<NN / 4, 256, 0, stream>>>(x, pos, pk, (float*)d_out);
}